// Round 2
// baseline (22974.609 us; speedup 1.0000x reference)
//
#include <hip/hip_runtime.h>
#include <hip/hip_bf16.h>

// ---------------------------------------------------------------------------
// SimpleCNN / TRM forward. Round 9 = round 8 with the wbar-clobber fixed.
// Round 8 failed because wbar (wave-barrier counters) lives at
// base+10485760, INSIDE pool1's range [0, 12845056) — and init_bar ran
// BEFORE conv1_pool, so conv1 output overwrote the zeroed counters ->
// every barrier spin passed instantly -> unsynchronized races -> inf.
// Fix: launch init_bar AFTER the whole fp32 prologue (that region is dead
// during the persistent kernel). Device code identical to round 8:
//  (1) WAVE-granular cross-block barriers (per-(group,wave) counters; the
//      data dependency is per row-tile: wave w of every block writes and
//      reads only h1/xs rows [rowA,rowA+16)). No __syncthreads in the loop.
//  (2) A-prefetch ring depth 8, distance 8, consume-then-prefetch.
// Math identical to rounds 2-8: split-bf16 MFMA, fp32 prologue.
// ---------------------------------------------------------------------------

typedef unsigned short ushort_t;
typedef __attribute__((ext_vector_type(8))) short short8;
typedef __attribute__((ext_vector_type(4))) float f32x4;

__device__ inline unsigned f2bf_rne(float v) {
    unsigned u = __float_as_uint(v);
    return (u + 0x7fffu + ((u >> 16) & 1u)) >> 16;
}
__device__ inline void split2(float v, ushort_t& h, ushort_t& l) {
    unsigned uh = f2bf_rne(v);
    h = (ushort_t)uh;
    float fh = __uint_as_float(uh << 16);
    l = (ushort_t)f2bf_rne(v - fh);
}

// ---------------- conv1 (1->16, 3x3 SAME, 28x28) + relu + maxpool2 ----------
__global__ __launch_bounds__(256) void conv1_pool(
    const float* __restrict__ in, const float* __restrict__ w,
    const float* __restrict__ bias, float* __restrict__ out)
{
    int idx = blockIdx.x * 256 + threadIdx.x;   // 1024*16*14*14
    int xo = idx % 14; int t = idx / 14;
    int yo = t % 14;  t /= 14;
    int oc = t % 16;  int b = t / 16;
    const float* ip = in + (size_t)b * 784;
    const float* wp = w + oc * 9;
    float win[4][4];
#pragma unroll
    for (int yy = 0; yy < 4; ++yy)
#pragma unroll
        for (int xx = 0; xx < 4; ++xx) {
            int y = 2 * yo + yy - 1, x = 2 * xo + xx - 1;
            win[yy][xx] = (y >= 0 && y < 28 && x >= 0 && x < 28) ? ip[y * 28 + x] : 0.f;
        }
    float bs = bias[oc];
    float m = -1e30f;
#pragma unroll
    for (int py = 0; py < 2; ++py)
#pragma unroll
        for (int px = 0; px < 2; ++px) {
            float s = bs;
#pragma unroll
            for (int dy = 0; dy < 3; ++dy)
#pragma unroll
                for (int dx = 0; dx < 3; ++dx)
                    s = fmaf(win[py + dy][px + dx], wp[dy * 3 + dx], s);
            m = fmaxf(m, s);
        }
    out[idx] = fmaxf(m, 0.f);
}

// ---------------- conv2 (16->32, 3x3 SAME, 14x14) + relu + maxpool2 ---------
__global__ __launch_bounds__(256) void conv2_pool(
    const float* __restrict__ in, const float* __restrict__ w,
    const float* __restrict__ bias, float* __restrict__ out)
{
    __shared__ float ws_[32 * 16 * 9];
    for (int i = threadIdx.x; i < 4608; i += 256) ws_[i] = w[i];
    __syncthreads();
    int idx = blockIdx.x * 256 + threadIdx.x;   // 1024*32*7*7
    int xo = idx % 7; int t = idx / 7;
    int yo = t % 7;  t /= 7;
    int oc = t % 32; int b = t / 32;
    const float* ip = in + (size_t)b * 16 * 196;
    float bs = bias[oc];
    float s00 = bs, s01 = bs, s10 = bs, s11 = bs;
    for (int ic = 0; ic < 16; ++ic) {
        const float* ipp = ip + ic * 196;
        float win[4][4];
#pragma unroll
        for (int yy = 0; yy < 4; ++yy)
#pragma unroll
            for (int xx = 0; xx < 4; ++xx) {
                int y = 2 * yo + yy - 1, x = 2 * xo + xx - 1;
                win[yy][xx] = (y >= 0 && y < 14 && x >= 0 && x < 14) ? ipp[y * 14 + x] : 0.f;
            }
        const float* wp = ws_ + (oc * 16 + ic) * 9;
#pragma unroll
        for (int dy = 0; dy < 3; ++dy)
#pragma unroll
            for (int dx = 0; dx < 3; ++dx) {
                float wv = wp[dy * 3 + dx];
                s00 = fmaf(win[0 + dy][0 + dx], wv, s00);
                s01 = fmaf(win[0 + dy][1 + dx], wv, s01);
                s10 = fmaf(win[1 + dy][0 + dx], wv, s10);
                s11 = fmaf(win[1 + dy][1 + dx], wv, s11);
            }
    }
    float m = fmaxf(fmaxf(s00, s01), fmaxf(s10, s11));
    out[idx] = fmaxf(m, 0.f);
}

// ---------------- fp32 tiled GEMM (prologue only: proj1, proj2) -------------
#define BMF 64
#define BNF 64
#define BKF 16

__global__ __launch_bounds__(256) void gemm_f32(
    const float* __restrict__ A0, const float* __restrict__ W,
    const float* __restrict__ bias, float* __restrict__ C,
    int M, int N, int K)
{
    __shared__ float As[BKF][BMF];
    __shared__ float Bs[BKF][BNF];
    const int tid = threadIdx.x;
    const int tx = tid % 16;
    const int ty = tid / 16;
    const int row0 = blockIdx.y * BMF;
    const int col0 = blockIdx.x * BNF;
    float acc[4][4] = {};
    const int ra = tid / 4;
    const int ca = 4 * (tid % 4);
    const int rb = tid / 16;
    const int cb = 4 * (tid % 16);
    for (int k0 = 0; k0 < K; k0 += BKF) {
        float4 v = *(const float4*)(A0 + (size_t)(row0 + ra) * K + k0 + ca);
        float4 bvec = *(const float4*)(W + (size_t)(k0 + rb) * N + col0 + cb);
        As[ca + 0][ra] = v.x;
        As[ca + 1][ra] = v.y;
        As[ca + 2][ra] = v.z;
        As[ca + 3][ra] = v.w;
        *(float4*)&Bs[rb][cb] = bvec;
        __syncthreads();
#pragma unroll
        for (int kk = 0; kk < BKF; ++kk) {
            float4 av = *(const float4*)&As[kk][ty * 4];
            float4 bv = *(const float4*)&Bs[kk][tx * 4];
            float a_[4] = {av.x, av.y, av.z, av.w};
            float b_[4] = {bv.x, bv.y, bv.z, bv.w};
#pragma unroll
            for (int i = 0; i < 4; ++i)
#pragma unroll
                for (int j = 0; j < 4; ++j)
                    acc[i][j] = fmaf(a_[i], b_[j], acc[i][j]);
        }
        __syncthreads();
    }
    float4 bv = *(const float4*)(bias + col0 + tx * 4);
    float bb[4] = {bv.x, bv.y, bv.z, bv.w};
#pragma unroll
    for (int i = 0; i < 4; ++i) {
        float4 o;
        o.x = fmaxf(acc[i][0] + bb[0], 0.f);
        o.y = fmaxf(acc[i][1] + bb[1], 0.f);
        o.z = fmaxf(acc[i][2] + bb[2], 0.f);
        o.w = fmaxf(acc[i][3] + bb[3], 0.f);
        *(float4*)(C + (size_t)(row0 + ty * 4 + i) * N + col0 + tx * 4) = o;
    }
}

// ---------------- weight prep: transpose + split ----------------------------
__global__ __launch_bounds__(256) void prep_wt(
    const float* __restrict__ w, ushort_t* __restrict__ th,
    ushort_t* __restrict__ tl, int K, int N)
{
    int idx = blockIdx.x * 256 + threadIdx.x;   // n*K + k
    int n = idx / K, k = idx % K;
    float v = w[(size_t)k * N + n];
    split2(v, th[idx], tl[idx]);
}

// ---------------- init: io = inp + out_e ; xs = split(io + lat_e) -----------
__global__ __launch_bounds__(256) void init_xs(
    const float* __restrict__ inpf, const float* __restrict__ oute,
    const float* __restrict__ late, float* __restrict__ io,
    ushort_t* __restrict__ xh, ushort_t* __restrict__ xl)
{
    int i = blockIdx.x * 256 + threadIdx.x;     // 1024*512
    float t = inpf[i] + oute[i];
    io[i] = t;
    split2(t + late[i], xh[i], xl[i]);
}

// ---------------- barrier init (MUST run after the fp32 prologue: wbar ------
// aliases pool1's dead tail [10485760, 12845056) which conv1_pool writes) ----
__global__ void init_bar(unsigned* bar, unsigned* wbar) {
    bar[threadIdx.x] = 0;          // [g*32]: final group barrier counters
    bar[threadIdx.x + 256] = 0;    // [384+x*8]: XCD slot-claim counters
    for (int i = threadIdx.x; i < 2048; i += 256) wbar[i] = 0;  // wave ctrs
}

// ---------------------------------------------------------------------------
// Per-(group,wave) cross-block barrier: wave w of all 32 blocks in group g
// sync among themselves only. release = workgroup fence (vmcnt drain; L1 is
// write-through so data is in the local L2); acquire = workgroup fence +
// vector-L1 invalidate. Counters 128B apart (no line sharing). Relaxed spin.
// Wave-internal reconvergence after the lane-0 branch is the wave "sync".
// ---------------------------------------------------------------------------
__device__ __forceinline__ void wave_barrier(unsigned* ctr, unsigned& tgt,
                                             int lane)
{
    if (lane == 0) {
        __builtin_amdgcn_fence(__ATOMIC_RELEASE, "workgroup");
        __hip_atomic_fetch_add(ctr, 1u, __ATOMIC_RELAXED,
                               __HIP_MEMORY_SCOPE_AGENT);
        while (__hip_atomic_load(ctr, __ATOMIC_RELAXED,
                                 __HIP_MEMORY_SCOPE_AGENT) < tgt)
            __builtin_amdgcn_s_sleep(1);
    }
    __builtin_amdgcn_fence(__ATOMIC_ACQUIRE, "workgroup");
    asm volatile("buffer_inv sc0" ::: "memory");   // vector L1 inv only
    tgt += 32;
}

// A-operand fragment load from global (MFMA 16x16x32 A layout:
// lane (li,q) holds A[row][q*8..q*8+8) at kpos offset).
__device__ __forceinline__ short8 afrag(const ushort_t* __restrict__ p,
                                        int row, int K, int kpos)
{
    return *(const short8*)(p + (size_t)row * K + kpos);
}

// ---------------------------------------------------------------------------
// Persistent TRM kernel. grid 256, 512 threads (8 waves, 2/SIMD), 1 block/CU
// (128KB LDS). Block self-assigns (g = physical XCD, slot = claim 0..31).
// Group g owns rows [g*128, g*128+128); wave w owns rows rowA = g*128+w*16.
// Block's fixed cols: GEMM1 c1 = slot*32 (W1 slice 64KB LDS), GEMM2
// c2 = slot*16 (W2 slice 64KB LDS). LDS weights in MFMA fragment order:
//   W1: [comp][s(0..15)][tj(0..1)][lane]*16B ; W2: [comp][s(0..31)][lane]*16B
// -> every ds_read_b128 is a wave-contiguous 1KB (zero bank conflicts).
// Main loop has NO __syncthreads: waves sync only with their row-tile peers
// in other blocks (per-(g,w) counters). LDS weights are read-only; io/latf/
// inpf epilogue state is same-wave private. A-prefetch: depth-8 ring,
// distance 8, consume-then-prefetch.
// ---------------------------------------------------------------------------
__global__ __launch_bounds__(512, 2) void trm_persist(
    ushort_t* __restrict__ xs_hi, ushort_t* __restrict__ xs_lo,
    ushort_t* __restrict__ h1_hi, ushort_t* __restrict__ h1_lo,
    const ushort_t* __restrict__ W1h, const ushort_t* __restrict__ W1l,
    const ushort_t* __restrict__ W2h, const ushort_t* __restrict__ W2l,
    const float* __restrict__ bb1, const float* __restrict__ bb2,
    float* __restrict__ io, const float* __restrict__ inpf,
    float* __restrict__ latf, float* __restrict__ outf,
    const float* __restrict__ hw, const float* __restrict__ hb,
    float* __restrict__ logits, unsigned* bar, unsigned* wbar)
{
    __shared__ __align__(16) unsigned char w1lds[65536];
    __shared__ __align__(16) unsigned char w2lds[65536];
    __shared__ int sh_gs;

    const int tid = threadIdx.x;
    const int w = tid >> 6, lane = tid & 63;
    const int q = lane >> 4, li = lane & 15;

    // ---- self-organize: group by PHYSICAL XCD, claim slot ----
    if (tid == 0) {
        unsigned xcc;
        asm volatile("s_getreg_b32 %0, hwreg(HW_REG_XCC_ID)" : "=s"(xcc));
        xcc &= 7u;
        unsigned s = __hip_atomic_fetch_add(bar + 384 + xcc * 8, 1u,
                                            __ATOMIC_RELAXED,
                                            __HIP_MEMORY_SCOPE_AGENT);
        sh_gs = (int)((xcc << 8) | (s & 31u));
    }
    __syncthreads();
    const int g = sh_gs >> 8;
    const int slot = sh_gs & 255;
    const int c1 = slot * 32;       // GEMM1 col base
    const int c2 = slot * 16;       // GEMM2 col base
    const int rowA = g * 128 + w * 16;
    unsigned* wctr = wbar + (g * 8 + w) * 32;   // 128B-spaced per-wave ctr

    // ---- preload weight slices into LDS in fragment order (once) ----
    for (int i = tid; i < 4096; i += 512) {               // W1: 2*32n*64c
        int comp = i >> 11;
        int rem = i & 2047;
        int n = rem >> 6, c = rem & 63;                   // n 0..31, c 0..63
        const ushort_t* src = (comp ? W1l : W1h) + (size_t)(c1 + n) * 512 + c * 8;
        int dst = ((((comp << 4) + (c >> 2)) * 2 + (n >> 4)) * 64 +
                   ((c & 3) * 16 + (n & 15))) * 16;
        *(uint4*)(w1lds + dst) = *(const uint4*)src;
    }
    for (int i = tid; i < 4096; i += 512) {               // W2: 2*16n*128c
        int comp = i >> 11;
        int rem = i & 2047;
        int n = rem >> 7, c = rem & 127;                  // n 0..15, c 0..127
        const ushort_t* src = (comp ? W2l : W2h) + (size_t)(c2 + n) * 1024 + c * 8;
        int dst = (((comp << 5) + (c >> 2)) * 64 + ((c & 3) * 16 + n)) * 16;
        *(uint4*)(w2lds + dst) = *(const uint4*)src;
    }
    __syncthreads();

    float bias1[2];
    bias1[0] = bb1[c1 + li];
    bias1[1] = bb1[c1 + 16 + li];
    float bias2 = bb2[c2 + li];
    unsigned tgt = 32;

    for (int step = 0; step < 336; ++step) {              // 48 sup * 7
        // ==== GEMM1: h1[16rows x 32cols] = relu(xs @ W1 + bb1), K=512 ====
        {
            f32x4 acc0 = {}, acc1 = {};
            short8 aF[8][2];                              // ring [slot][comp]
#pragma unroll
            for (int p = 0; p < 8; ++p) {
                int kp = p * 32 + q * 8;
                aF[p][0] = afrag(xs_hi, rowA + li, 512, kp);
                aF[p][1] = afrag(xs_lo, rowA + li, 512, kp);
            }
#pragma unroll
            for (int s = 0; s < 16; ++s) {
                // CONSUME first (copy out of ring)...
                short8 ah = aF[s & 7][0], al = aF[s & 7][1];
                // ...THEN prefetch into the now-free slot ((s+8)&7 == s&7)
                if (s + 8 < 16) {
                    int kp = (s + 8) * 32 + q * 8;
                    aF[(s + 8) & 7][0] = afrag(xs_hi, rowA + li, 512, kp);
                    aF[(s + 8) & 7][1] = afrag(xs_lo, rowA + li, 512, kp);
                }
                const int base = (s * 2 * 64 + lane) * 16;
                short8 bh0 = *(const short8*)(w1lds + base);
                short8 bh1 = *(const short8*)(w1lds + base + 1024);
                short8 bl0 = *(const short8*)(w1lds + 32768 + base);
                short8 bl1 = *(const short8*)(w1lds + 32768 + base + 1024);
                acc0 = __builtin_amdgcn_mfma_f32_16x16x32_bf16(ah, bh0, acc0, 0, 0, 0);
                acc0 = __builtin_amdgcn_mfma_f32_16x16x32_bf16(ah, bl0, acc0, 0, 0, 0);
                acc0 = __builtin_amdgcn_mfma_f32_16x16x32_bf16(al, bh0, acc0, 0, 0, 0);
                acc0 = __builtin_amdgcn_mfma_f32_16x16x32_bf16(al, bl0, acc0, 0, 0, 0);
                acc1 = __builtin_amdgcn_mfma_f32_16x16x32_bf16(ah, bh1, acc1, 0, 0, 0);
                acc1 = __builtin_amdgcn_mfma_f32_16x16x32_bf16(ah, bl1, acc1, 0, 0, 0);
                acc1 = __builtin_amdgcn_mfma_f32_16x16x32_bf16(al, bh1, acc1, 0, 0, 0);
                acc1 = __builtin_amdgcn_mfma_f32_16x16x32_bf16(al, bl1, acc1, 0, 0, 0);
            }
            // epilogue: split h1 (C layout: col=lane&15, row=quad*4+reg)
#pragma unroll
            for (int tj = 0; tj < 2; ++tj) {
                int colg = c1 + tj * 16 + li;
                float bv = bias1[tj];
#pragma unroll
                for (int rr = 0; rr < 4; ++rr) {
                    int rowg = rowA + q * 4 + rr;
                    size_t idx = (size_t)rowg * 1024 + colg;
                    float v = fmaxf((tj ? acc1[rr] : acc0[rr]) + bv, 0.f);
                    split2(v, h1_hi[idx], h1_lo[idx]);
                }
            }
        }
        wave_barrier(wctr, tgt, lane);

        // ==== GEMM2: xs'[16rows x 16cols] = f(relu(h1 @ W2 + bb2)), K=1024 ====
        {
            int im = step % 7;
            int mode = (im < 5) ? 1 : ((im == 5) ? 2 : 3);
            f32x4 acc = {};
            short8 aF[8][2];
#pragma unroll
            for (int p = 0; p < 8; ++p) {
                int kp = p * 32 + q * 8;
                aF[p][0] = afrag(h1_hi, rowA + li, 1024, kp);
                aF[p][1] = afrag(h1_lo, rowA + li, 1024, kp);
            }
#pragma unroll
            for (int s = 0; s < 32; ++s) {
                short8 ah = aF[s & 7][0], al = aF[s & 7][1];   // consume first
                if (s + 8 < 32) {
                    int kp = (s + 8) * 32 + q * 8;
                    aF[(s + 8) & 7][0] = afrag(h1_hi, rowA + li, 1024, kp);
                    aF[(s + 8) & 7][1] = afrag(h1_lo, rowA + li, 1024, kp);
                }
                const int base = (s * 64 + lane) * 16;
                short8 bh = *(const short8*)(w2lds + base);
                short8 bl = *(const short8*)(w2lds + 32768 + base);
                acc = __builtin_amdgcn_mfma_f32_16x16x32_bf16(ah, bh, acc, 0, 0, 0);
                acc = __builtin_amdgcn_mfma_f32_16x16x32_bf16(ah, bl, acc, 0, 0, 0);
                acc = __builtin_amdgcn_mfma_f32_16x16x32_bf16(al, bh, acc, 0, 0, 0);
                acc = __builtin_amdgcn_mfma_f32_16x16x32_bf16(al, bl, acc, 0, 0, 0);
            }
            // epilogue with recursion-state chaining (io/latf/inpf are
            // same-wave private: this wave wrote these rows/cols last time)
            int colg = c2 + li;
#pragma unroll
            for (int rr = 0; rr < 4; ++rr) {
                int rowg = rowA + q * 4 + rr;
                size_t idx = (size_t)rowg * 512 + colg;
                float v = fmaxf(acc[rr] + bias2, 0.f);
                if (mode == 1) {
                    split2(io[idx] + v, xs_hi[idx], xs_lo[idx]);
                } else if (mode == 2) {
                    split2(inpf[idx] + v, xs_hi[idx], xs_lo[idx]);
                    latf[idx] = v;
                } else {
                    outf[idx] = v;
                    float t2 = inpf[idx] + v;
                    io[idx] = t2;
                    split2(t2 + latf[idx], xs_hi[idx], xs_lo[idx]);
                }
            }
        }
        wave_barrier(wctr, tgt, lane);
    }

    // ---- final FULL-group barrier (all 8 waves x 32 blocks) before head ----
    if (lane == 0) {
        __builtin_amdgcn_fence(__ATOMIC_RELEASE, "workgroup");
        __hip_atomic_fetch_add(bar + g * 32, 1u, __ATOMIC_RELAXED,
                               __HIP_MEMORY_SCOPE_AGENT);
        while (__hip_atomic_load(bar + g * 32, __ATOMIC_RELAXED,
                                 __HIP_MEMORY_SCOPE_AGENT) < 256u)
            __builtin_amdgcn_s_sleep(1);
    }
    __builtin_amdgcn_fence(__ATOMIC_ACQUIRE, "workgroup");
    asm volatile("buffer_inv sc0" ::: "memory");

    // ---- head: logits rows [g*128, g*128+128), 1280 elems per group ----
    {
        int idx = slot * 512 + tid;
        if (idx < 1280) {
            int rloc = idx / 10, j = idx % 10;
            int row = g * 128 + rloc;
            const float* r = outf + (size_t)row * 512;
            float s = hb[j];
            for (int k = 0; k < 512; ++k) s = fmaf(r[k], hw[k * 10 + j], s);
            logits[row * 10 + j] = s;
        }
    }
}

extern "C" void kernel_launch(void* const* d_in, const int* in_sizes, int n_in,
                              void* d_out, int out_size, void* d_ws, size_t ws_size,
                              hipStream_t stream)
{
    const float* raw   = (const float*)d_in[0];
    const float* out_e = (const float*)d_in[1];
    const float* lat_e = (const float*)d_in[2];
    const float* c1w = (const float*)d_in[3];
    const float* c1b = (const float*)d_in[4];
    const float* c2w = (const float*)d_in[5];
    const float* c2b = (const float*)d_in[6];
    const float* pw1 = (const float*)d_in[7];
    const float* pb1 = (const float*)d_in[8];
    const float* pw2 = (const float*)d_in[9];
    const float* pb2 = (const float*)d_in[10];
    const float* bw1 = (const float*)d_in[11];
    const float* bb1 = (const float*)d_in[12];
    const float* bw2 = (const float*)d_in[13];
    const float* bb2 = (const float*)d_in[14];
    const float* hw  = (const float*)d_in[15];
    const float* hb  = (const float*)d_in[16];
    // d_in[17]=Nsup(16), d_in[18]=n_latent(6): fixed, hard-coded.

    char* base = (char*)d_ws;
    float*    pool1  = (float*)   (base + 0);          // conv1 out (pre-backbone)
    ushort_t* h1_hi  = (ushort_t*)(base + 0);
    ushort_t* h1_lo  = (ushort_t*)(base + 2097152);
    ushort_t* xs_hi  = (ushort_t*)(base + 4194304);
    ushort_t* xs_lo  = (ushort_t*)(base + 5242880);
    float*    io     = (float*)   (base + 6291456);
    float*    latf   = (float*)   (base + 8388608);
    unsigned* wbar   = (unsigned*)(base + 10485760);   // 8KB wave ctrs — in
                                                       // pool1's DEAD tail;
                                                       // init_bar must run
                                                       // after the prologue!
    float*    h1f    = (float*)   (base + 0);          // proj1 out (pre-backbone)
    float*    h      = (float*)   (base + 12845056);   // conv2 out fp32
    float*    inpf   = (float*)   (base + 19267584);
    float*    outf   = (float*)   (base + 21364736);
    ushort_t* bW1t_h = (ushort_t*)(base + 23461888);   // [1024n][512k]
    ushort_t* bW1t_l = (ushort_t*)(base + 24510464);
    ushort_t* bW2t_h = (ushort_t*)(base + 25559040);   // [512n][1024k]
    ushort_t* bW2t_l = (ushort_t*)(base + 26607616);
    unsigned* bar    = (unsigned*)(base + 27656192);   // 2KB final-bar/claim

    // weight prep (every launch; ws is re-poisoned by harness)
    prep_wt<<<2048, 256, 0, stream>>>(bw1, bW1t_h, bW1t_l, 512, 1024);
    prep_wt<<<2048, 256, 0, stream>>>(bw2, bW2t_h, bW2t_l, 1024, 512);

    // fp32 prologue
    conv1_pool<<<3211264 / 256, 256, 0, stream>>>(raw, c1w, c1b, pool1);
    conv2_pool<<<1605632 / 256, 256, 0, stream>>>(pool1, c2w, c2b, h);
    gemm_f32<<<dim3(16, 16), 256, 0, stream>>>(h, pw1, pb1, h1f, 1024, 1024, 1568);
    gemm_f32<<<dim3(8, 16), 256, 0, stream>>>(h1f, pw2, pb2, inpf, 1024, 512, 1024);
    init_xs<<<2048, 256, 0, stream>>>(inpf, out_e, lat_e, io, xs_hi, xs_lo);

    // barrier init LAST (wbar aliases pool1's dead tail; nothing may write
    // the region between here and trm_persist)
    init_bar<<<1, 256, 0, stream>>>(bar, wbar);

    // the whole recursion + head in ONE persistent kernel
    trm_persist<<<256, 512, 0, stream>>>(
        xs_hi, xs_lo, h1_hi, h1_lo, bW1t_h, bW1t_l, bW2t_h, bW2t_l,
        bb1, bb2, io, inpf, latf, outf, hw, hb, (float*)d_out, bar, wbar);
}

// Round 3
// 8396.210 us; speedup vs baseline: 2.7363x; 2.7363x over previous
//
#include <hip/hip_runtime.h>
#include <hip/hip_bf16.h>

// ---------------------------------------------------------------------------
// SimpleCNN / TRM forward. Round 10 = REVERT to round-7 sync structure
// (block-level group barrier, proven 8.2ms; round 9's wave-granular barriers
// were 3x WORSE: 8 async buffer_inv/spin chains per CU trashed L1/L2
// locality). One isolated change on top: deeper A-prefetch rings that the
// compiler CANNOT sink. Round 9's rocprof showed VGPR_Count stuck at 88 ==
// round 7's depth-4 ring: the scheduler sank the depth-8 prefetches back to
// their uses. Fix: sched_barrier(0) immediately after each prefetch issue
// pins the loads at their issue point (waitcnt insertion still happens at
// the consume point, so latency is covered, not exposed).
//   GEMM1: ring depth 8  (per-iter ~60-80cy -> ~500cy cover >= L2 ~300cy)
//   GEMM2: ring depth 16 (per-iter ~40-50cy -> ~700cy cover)
// Tell-tale: VGPR_Count should rise to ~150-190. Math identical to r2-r9.
// ---------------------------------------------------------------------------

typedef unsigned short ushort_t;
typedef __attribute__((ext_vector_type(8))) short short8;
typedef __attribute__((ext_vector_type(4))) float f32x4;

__device__ inline unsigned f2bf_rne(float v) {
    unsigned u = __float_as_uint(v);
    return (u + 0x7fffu + ((u >> 16) & 1u)) >> 16;
}
__device__ inline void split2(float v, ushort_t& h, ushort_t& l) {
    unsigned uh = f2bf_rne(v);
    h = (ushort_t)uh;
    float fh = __uint_as_float(uh << 16);
    l = (ushort_t)f2bf_rne(v - fh);
}

// ---------------- conv1 (1->16, 3x3 SAME, 28x28) + relu + maxpool2 ----------
__global__ __launch_bounds__(256) void conv1_pool(
    const float* __restrict__ in, const float* __restrict__ w,
    const float* __restrict__ bias, float* __restrict__ out)
{
    int idx = blockIdx.x * 256 + threadIdx.x;   // 1024*16*14*14
    int xo = idx % 14; int t = idx / 14;
    int yo = t % 14;  t /= 14;
    int oc = t % 16;  int b = t / 16;
    const float* ip = in + (size_t)b * 784;
    const float* wp = w + oc * 9;
    float win[4][4];
#pragma unroll
    for (int yy = 0; yy < 4; ++yy)
#pragma unroll
        for (int xx = 0; xx < 4; ++xx) {
            int y = 2 * yo + yy - 1, x = 2 * xo + xx - 1;
            win[yy][xx] = (y >= 0 && y < 28 && x >= 0 && x < 28) ? ip[y * 28 + x] : 0.f;
        }
    float bs = bias[oc];
    float m = -1e30f;
#pragma unroll
    for (int py = 0; py < 2; ++py)
#pragma unroll
        for (int px = 0; px < 2; ++px) {
            float s = bs;
#pragma unroll
            for (int dy = 0; dy < 3; ++dy)
#pragma unroll
                for (int dx = 0; dx < 3; ++dx)
                    s = fmaf(win[py + dy][px + dx], wp[dy * 3 + dx], s);
            m = fmaxf(m, s);
        }
    out[idx] = fmaxf(m, 0.f);
}

// ---------------- conv2 (16->32, 3x3 SAME, 14x14) + relu + maxpool2 ---------
__global__ __launch_bounds__(256) void conv2_pool(
    const float* __restrict__ in, const float* __restrict__ w,
    const float* __restrict__ bias, float* __restrict__ out)
{
    __shared__ float ws_[32 * 16 * 9];
    for (int i = threadIdx.x; i < 4608; i += 256) ws_[i] = w[i];
    __syncthreads();
    int idx = blockIdx.x * 256 + threadIdx.x;   // 1024*32*7*7
    int xo = idx % 7; int t = idx / 7;
    int yo = t % 7;  t /= 7;
    int oc = t % 32; int b = t / 32;
    const float* ip = in + (size_t)b * 16 * 196;
    float bs = bias[oc];
    float s00 = bs, s01 = bs, s10 = bs, s11 = bs;
    for (int ic = 0; ic < 16; ++ic) {
        const float* ipp = ip + ic * 196;
        float win[4][4];
#pragma unroll
        for (int yy = 0; yy < 4; ++yy)
#pragma unroll
            for (int xx = 0; xx < 4; ++xx) {
                int y = 2 * yo + yy - 1, x = 2 * xo + xx - 1;
                win[yy][xx] = (y >= 0 && y < 14 && x >= 0 && x < 14) ? ipp[y * 14 + x] : 0.f;
            }
        const float* wp = ws_ + (oc * 16 + ic) * 9;
#pragma unroll
        for (int dy = 0; dy < 3; ++dy)
#pragma unroll
            for (int dx = 0; dx < 3; ++dx) {
                float wv = wp[dy * 3 + dx];
                s00 = fmaf(win[0 + dy][0 + dx], wv, s00);
                s01 = fmaf(win[0 + dy][1 + dx], wv, s01);
                s10 = fmaf(win[1 + dy][0 + dx], wv, s10);
                s11 = fmaf(win[1 + dy][1 + dx], wv, s11);
            }
    }
    float m = fmaxf(fmaxf(s00, s01), fmaxf(s10, s11));
    out[idx] = fmaxf(m, 0.f);
}

// ---------------- fp32 tiled GEMM (prologue only: proj1, proj2) -------------
#define BMF 64
#define BNF 64
#define BKF 16

__global__ __launch_bounds__(256) void gemm_f32(
    const float* __restrict__ A0, const float* __restrict__ W,
    const float* __restrict__ bias, float* __restrict__ C,
    int M, int N, int K)
{
    __shared__ float As[BKF][BMF];
    __shared__ float Bs[BKF][BNF];
    const int tid = threadIdx.x;
    const int tx = tid % 16;
    const int ty = tid / 16;
    const int row0 = blockIdx.y * BMF;
    const int col0 = blockIdx.x * BNF;
    float acc[4][4] = {};
    const int ra = tid / 4;
    const int ca = 4 * (tid % 4);
    const int rb = tid / 16;
    const int cb = 4 * (tid % 16);
    for (int k0 = 0; k0 < K; k0 += BKF) {
        float4 v = *(const float4*)(A0 + (size_t)(row0 + ra) * K + k0 + ca);
        float4 bvec = *(const float4*)(W + (size_t)(k0 + rb) * N + col0 + cb);
        As[ca + 0][ra] = v.x;
        As[ca + 1][ra] = v.y;
        As[ca + 2][ra] = v.z;
        As[ca + 3][ra] = v.w;
        *(float4*)&Bs[rb][cb] = bvec;
        __syncthreads();
#pragma unroll
        for (int kk = 0; kk < BKF; ++kk) {
            float4 av = *(const float4*)&As[kk][ty * 4];
            float4 bv = *(const float4*)&Bs[kk][tx * 4];
            float a_[4] = {av.x, av.y, av.z, av.w};
            float b_[4] = {bv.x, bv.y, bv.z, bv.w};
#pragma unroll
            for (int i = 0; i < 4; ++i)
#pragma unroll
                for (int j = 0; j < 4; ++j)
                    acc[i][j] = fmaf(a_[i], b_[j], acc[i][j]);
        }
        __syncthreads();
    }
    float4 bv = *(const float4*)(bias + col0 + tx * 4);
    float bb[4] = {bv.x, bv.y, bv.z, bv.w};
#pragma unroll
    for (int i = 0; i < 4; ++i) {
        float4 o;
        o.x = fmaxf(acc[i][0] + bb[0], 0.f);
        o.y = fmaxf(acc[i][1] + bb[1], 0.f);
        o.z = fmaxf(acc[i][2] + bb[2], 0.f);
        o.w = fmaxf(acc[i][3] + bb[3], 0.f);
        *(float4*)(C + (size_t)(row0 + ty * 4 + i) * N + col0 + tx * 4) = o;
    }
}

// ---------------- weight prep: transpose + split ----------------------------
__global__ __launch_bounds__(256) void prep_wt(
    const float* __restrict__ w, ushort_t* __restrict__ th,
    ushort_t* __restrict__ tl, int K, int N)
{
    int idx = blockIdx.x * 256 + threadIdx.x;   // n*K + k
    int n = idx / K, k = idx % K;
    float v = w[(size_t)k * N + n];
    split2(v, th[idx], tl[idx]);
}

// ---------------- init: io = inp + out_e ; xs = split(io + lat_e) -----------
__global__ __launch_bounds__(256) void init_xs(
    const float* __restrict__ inpf, const float* __restrict__ oute,
    const float* __restrict__ late, float* __restrict__ io,
    ushort_t* __restrict__ xh, ushort_t* __restrict__ xl)
{
    int i = blockIdx.x * 256 + threadIdx.x;     // 1024*512
    float t = inpf[i] + oute[i];
    io[i] = t;
    split2(t + late[i], xh[i], xl[i]);
}

// ---------------- barrier init ---------------------------------------------
__global__ void init_bar(unsigned* bar) {
    bar[threadIdx.x] = 0;          // [0..255]: group barrier counters (g*32)
    bar[threadIdx.x + 256] = 0;    // [384+x*8]: XCD slot-claim counters
}

// ---------------------------------------------------------------------------
// Per-XCD-group (32-block) barrier — round-7 structure (proven). Groups are
// same-XCD by construction (1 block/CU, 32 CUs/XCD). release = workgroup
// fence; acquire = workgroup fence + one vector-L1 inv by tid 0 only.
// ---------------------------------------------------------------------------
__device__ __forceinline__ void group_barrier(unsigned* bar, int g,
                                              unsigned& tgt)
{
    __syncthreads();
    if (threadIdx.x == 0) {
        __builtin_amdgcn_fence(__ATOMIC_RELEASE, "workgroup");
        __hip_atomic_fetch_add(bar + g * 32, 1u, __ATOMIC_RELAXED,
                               __HIP_MEMORY_SCOPE_AGENT);
        while (__hip_atomic_load(bar + g * 32, __ATOMIC_RELAXED,
                                 __HIP_MEMORY_SCOPE_AGENT) < tgt)
            __builtin_amdgcn_s_sleep(1);
        __builtin_amdgcn_fence(__ATOMIC_ACQUIRE, "workgroup");
        asm volatile("buffer_inv sc0" ::: "memory");   // vector L1 inv only
    }
    tgt += 32;
    __syncthreads();
}

// A-operand fragment load from global (MFMA 16x16x32 A layout:
// lane (li,q) holds A[row][q*8..q*8+8) at kpos offset).
__device__ __forceinline__ short8 afrag(const ushort_t* __restrict__ p,
                                        int row, int K, int kpos)
{
    return *(const short8*)(p + (size_t)row * K + kpos);
}

// ---------------------------------------------------------------------------
// Persistent TRM kernel. grid 256, 512 threads (8 waves, 2/SIMD), 1 block/CU
// (128KB LDS). Block self-assigns (g = physical XCD, slot = claim 0..31).
// Group g owns rows [g*128, g*128+128); wave w owns rows rowA = g*128+w*16.
// Block's fixed cols: GEMM1 c1 = slot*32 (W1 slice 64KB LDS), GEMM2
// c2 = slot*16 (W2 slice 64KB LDS). LDS weights in MFMA fragment order:
//   W1: [comp][s(0..15)][tj(0..1)][lane]*16B ; W2: [comp][s(0..31)][lane]*16B
// -> every ds_read_b128 is a wave-contiguous 1KB (zero bank conflicts).
// A-prefetch: GEMM1 ring-8, GEMM2 ring-16; consume-then-prefetch; each
// prefetch pair pinned with sched_barrier(0) so the scheduler can't sink it.
// ---------------------------------------------------------------------------
__global__ __launch_bounds__(512, 2) void trm_persist(
    ushort_t* __restrict__ xs_hi, ushort_t* __restrict__ xs_lo,
    ushort_t* __restrict__ h1_hi, ushort_t* __restrict__ h1_lo,
    const ushort_t* __restrict__ W1h, const ushort_t* __restrict__ W1l,
    const ushort_t* __restrict__ W2h, const ushort_t* __restrict__ W2l,
    const float* __restrict__ bb1, const float* __restrict__ bb2,
    float* __restrict__ io, const float* __restrict__ inpf,
    float* __restrict__ latf, float* __restrict__ outf,
    const float* __restrict__ hw, const float* __restrict__ hb,
    float* __restrict__ logits, unsigned* bar)
{
    __shared__ __align__(16) unsigned char w1lds[65536];
    __shared__ __align__(16) unsigned char w2lds[65536];
    __shared__ int sh_gs;

    const int tid = threadIdx.x;
    const int w = tid >> 6, lane = tid & 63;
    const int q = lane >> 4, li = lane & 15;

    // ---- self-organize: group by PHYSICAL XCD, claim slot ----
    if (tid == 0) {
        unsigned xcc;
        asm volatile("s_getreg_b32 %0, hwreg(HW_REG_XCC_ID)" : "=s"(xcc));
        xcc &= 7u;
        unsigned s = __hip_atomic_fetch_add(bar + 384 + xcc * 8, 1u,
                                            __ATOMIC_RELAXED,
                                            __HIP_MEMORY_SCOPE_AGENT);
        sh_gs = (int)((xcc << 8) | (s & 31u));
    }
    __syncthreads();
    const int g = sh_gs >> 8;
    const int slot = sh_gs & 255;
    const int c1 = slot * 32;       // GEMM1 col base
    const int c2 = slot * 16;       // GEMM2 col base
    const int rowA = g * 128 + w * 16;

    // ---- preload weight slices into LDS in fragment order (once) ----
    for (int i = tid; i < 4096; i += 512) {               // W1: 2*32n*64c
        int comp = i >> 11;
        int rem = i & 2047;
        int n = rem >> 6, c = rem & 63;                   // n 0..31, c 0..63
        const ushort_t* src = (comp ? W1l : W1h) + (size_t)(c1 + n) * 512 + c * 8;
        int dst = ((((comp << 4) + (c >> 2)) * 2 + (n >> 4)) * 64 +
                   ((c & 3) * 16 + (n & 15))) * 16;
        *(uint4*)(w1lds + dst) = *(const uint4*)src;
    }
    for (int i = tid; i < 4096; i += 512) {               // W2: 2*16n*128c
        int comp = i >> 11;
        int rem = i & 2047;
        int n = rem >> 7, c = rem & 127;                  // n 0..15, c 0..127
        const ushort_t* src = (comp ? W2l : W2h) + (size_t)(c2 + n) * 1024 + c * 8;
        int dst = (((comp << 5) + (c >> 2)) * 64 + ((c & 3) * 16 + n)) * 16;
        *(uint4*)(w2lds + dst) = *(const uint4*)src;
    }
    __syncthreads();

    float bias1[2];
    bias1[0] = bb1[c1 + li];
    bias1[1] = bb1[c1 + 16 + li];
    float bias2 = bb2[c2 + li];
    unsigned tgt = 32;

    for (int step = 0; step < 336; ++step) {              // 48 sup * 7
        // ==== GEMM1: h1[16rows x 32cols] = relu(xs @ W1 + bb1), K=512 ====
        {
            f32x4 acc0 = {}, acc1 = {};
            short8 aF[8][2];                              // ring [slot][comp]
#pragma unroll
            for (int p = 0; p < 8; ++p) {
                int kp = p * 32 + q * 8;
                aF[p][0] = afrag(xs_hi, rowA + li, 512, kp);
                aF[p][1] = afrag(xs_lo, rowA + li, 512, kp);
            }
            __builtin_amdgcn_sched_barrier(0);            // pin prologue loads
#pragma unroll
            for (int s = 0; s < 16; ++s) {
                // CONSUME first (copy out of ring)...
                short8 ah = aF[s & 7][0], al = aF[s & 7][1];
                // ...THEN prefetch into the freed slot ((s+8)&7 == s&7)
                if (s + 8 < 16) {
                    int kp = (s + 8) * 32 + q * 8;
                    aF[(s + 8) & 7][0] = afrag(xs_hi, rowA + li, 512, kp);
                    aF[(s + 8) & 7][1] = afrag(xs_lo, rowA + li, 512, kp);
                }
                __builtin_amdgcn_sched_barrier(0);        // pin prefetch issue
                const int base = (s * 2 * 64 + lane) * 16;
                short8 bh0 = *(const short8*)(w1lds + base);
                short8 bh1 = *(const short8*)(w1lds + base + 1024);
                short8 bl0 = *(const short8*)(w1lds + 32768 + base);
                short8 bl1 = *(const short8*)(w1lds + 32768 + base + 1024);
                acc0 = __builtin_amdgcn_mfma_f32_16x16x32_bf16(ah, bh0, acc0, 0, 0, 0);
                acc0 = __builtin_amdgcn_mfma_f32_16x16x32_bf16(ah, bl0, acc0, 0, 0, 0);
                acc0 = __builtin_amdgcn_mfma_f32_16x16x32_bf16(al, bh0, acc0, 0, 0, 0);
                acc0 = __builtin_amdgcn_mfma_f32_16x16x32_bf16(al, bl0, acc0, 0, 0, 0);
                acc1 = __builtin_amdgcn_mfma_f32_16x16x32_bf16(ah, bh1, acc1, 0, 0, 0);
                acc1 = __builtin_amdgcn_mfma_f32_16x16x32_bf16(ah, bl1, acc1, 0, 0, 0);
                acc1 = __builtin_amdgcn_mfma_f32_16x16x32_bf16(al, bh1, acc1, 0, 0, 0);
                acc1 = __builtin_amdgcn_mfma_f32_16x16x32_bf16(al, bl1, acc1, 0, 0, 0);
            }
            // epilogue: split h1 (C layout: col=lane&15, row=quad*4+reg)
#pragma unroll
            for (int tj = 0; tj < 2; ++tj) {
                int colg = c1 + tj * 16 + li;
                float bv = bias1[tj];
#pragma unroll
                for (int rr = 0; rr < 4; ++rr) {
                    int rowg = rowA + q * 4 + rr;
                    size_t idx = (size_t)rowg * 1024 + colg;
                    float v = fmaxf((tj ? acc1[rr] : acc0[rr]) + bv, 0.f);
                    split2(v, h1_hi[idx], h1_lo[idx]);
                }
            }
        }
        group_barrier(bar, g, tgt);

        // ==== GEMM2: xs'[16rows x 16cols] = f(relu(h1 @ W2 + bb2)), K=1024 ====
        {
            int im = step % 7;
            int mode = (im < 5) ? 1 : ((im == 5) ? 2 : 3);
            f32x4 acc = {};
            short8 aF[16][2];                             // ring [slot][comp]
#pragma unroll
            for (int p = 0; p < 16; ++p) {
                int kp = p * 32 + q * 8;
                aF[p][0] = afrag(h1_hi, rowA + li, 1024, kp);
                aF[p][1] = afrag(h1_lo, rowA + li, 1024, kp);
            }
            __builtin_amdgcn_sched_barrier(0);            // pin prologue loads
#pragma unroll
            for (int s = 0; s < 32; ++s) {
                short8 ah = aF[s & 15][0], al = aF[s & 15][1];  // consume first
                if (s + 16 < 32) {
                    int kp = (s + 16) * 32 + q * 8;
                    aF[(s + 16) & 15][0] = afrag(h1_hi, rowA + li, 1024, kp);
                    aF[(s + 16) & 15][1] = afrag(h1_lo, rowA + li, 1024, kp);
                }
                __builtin_amdgcn_sched_barrier(0);        // pin prefetch issue
                const int base = (s * 64 + lane) * 16;
                short8 bh = *(const short8*)(w2lds + base);
                short8 bl = *(const short8*)(w2lds + 32768 + base);
                acc = __builtin_amdgcn_mfma_f32_16x16x32_bf16(ah, bh, acc, 0, 0, 0);
                acc = __builtin_amdgcn_mfma_f32_16x16x32_bf16(ah, bl, acc, 0, 0, 0);
                acc = __builtin_amdgcn_mfma_f32_16x16x32_bf16(al, bh, acc, 0, 0, 0);
                acc = __builtin_amdgcn_mfma_f32_16x16x32_bf16(al, bl, acc, 0, 0, 0);
            }
            // epilogue with recursion-state chaining
            int colg = c2 + li;
#pragma unroll
            for (int rr = 0; rr < 4; ++rr) {
                int rowg = rowA + q * 4 + rr;
                size_t idx = (size_t)rowg * 512 + colg;
                float v = fmaxf(acc[rr] + bias2, 0.f);
                if (mode == 1) {
                    split2(io[idx] + v, xs_hi[idx], xs_lo[idx]);
                } else if (mode == 2) {
                    split2(inpf[idx] + v, xs_hi[idx], xs_lo[idx]);
                    latf[idx] = v;
                } else {
                    outf[idx] = v;
                    float t2 = inpf[idx] + v;
                    io[idx] = t2;
                    split2(t2 + latf[idx], xs_hi[idx], xs_lo[idx]);
                }
            }
        }
        group_barrier(bar, g, tgt);
    }

    // ---- head: logits rows [g*128, g*128+128), 1280 elems per group ----
    // (last loop iteration ended with a full group barrier; outf is visible)
    {
        int idx = slot * 512 + tid;
        if (idx < 1280) {
            int rloc = idx / 10, j = idx % 10;
            int row = g * 128 + rloc;
            const float* r = outf + (size_t)row * 512;
            float s = hb[j];
            for (int k = 0; k < 512; ++k) s = fmaf(r[k], hw[k * 10 + j], s);
            logits[row * 10 + j] = s;
        }
    }
}

extern "C" void kernel_launch(void* const* d_in, const int* in_sizes, int n_in,
                              void* d_out, int out_size, void* d_ws, size_t ws_size,
                              hipStream_t stream)
{
    const float* raw   = (const float*)d_in[0];
    const float* out_e = (const float*)d_in[1];
    const float* lat_e = (const float*)d_in[2];
    const float* c1w = (const float*)d_in[3];
    const float* c1b = (const float*)d_in[4];
    const float* c2w = (const float*)d_in[5];
    const float* c2b = (const float*)d_in[6];
    const float* pw1 = (const float*)d_in[7];
    const float* pb1 = (const float*)d_in[8];
    const float* pw2 = (const float*)d_in[9];
    const float* pb2 = (const float*)d_in[10];
    const float* bw1 = (const float*)d_in[11];
    const float* bb1 = (const float*)d_in[12];
    const float* bw2 = (const float*)d_in[13];
    const float* bb2 = (const float*)d_in[14];
    const float* hw  = (const float*)d_in[15];
    const float* hb  = (const float*)d_in[16];
    // d_in[17]=Nsup(16), d_in[18]=n_latent(6): fixed, hard-coded.

    char* base = (char*)d_ws;
    float*    pool1  = (float*)   (base + 0);          // conv1 out (pre-backbone)
    ushort_t* h1_hi  = (ushort_t*)(base + 0);
    ushort_t* h1_lo  = (ushort_t*)(base + 2097152);
    ushort_t* xs_hi  = (ushort_t*)(base + 4194304);
    ushort_t* xs_lo  = (ushort_t*)(base + 5242880);
    float*    io     = (float*)   (base + 6291456);
    float*    latf   = (float*)   (base + 8388608);
    float*    h1f    = (float*)   (base + 0);          // proj1 out (pre-backbone)
    float*    h      = (float*)   (base + 12845056);   // conv2 out fp32
    float*    inpf   = (float*)   (base + 19267584);
    float*    outf   = (float*)   (base + 21364736);
    ushort_t* bW1t_h = (ushort_t*)(base + 23461888);   // [1024n][512k]
    ushort_t* bW1t_l = (ushort_t*)(base + 24510464);
    ushort_t* bW2t_h = (ushort_t*)(base + 25559040);   // [512n][1024k]
    ushort_t* bW2t_l = (ushort_t*)(base + 26607616);
    unsigned* bar    = (unsigned*)(base + 27656192);   // 2KB barrier/claim

    // weight prep (every launch; ws is re-poisoned by harness)
    prep_wt<<<2048, 256, 0, stream>>>(bw1, bW1t_h, bW1t_l, 512, 1024);
    prep_wt<<<2048, 256, 0, stream>>>(bw2, bW2t_h, bW2t_l, 1024, 512);

    // fp32 prologue
    conv1_pool<<<3211264 / 256, 256, 0, stream>>>(raw, c1w, c1b, pool1);
    conv2_pool<<<1605632 / 256, 256, 0, stream>>>(pool1, c2w, c2b, h);
    gemm_f32<<<dim3(16, 16), 256, 0, stream>>>(h, pw1, pb1, h1f, 1024, 1024, 1568);
    gemm_f32<<<dim3(8, 16), 256, 0, stream>>>(h1f, pw2, pb2, inpf, 1024, 512, 1024);
    init_xs<<<2048, 256, 0, stream>>>(inpf, out_e, lat_e, io, xs_hi, xs_lo);

    // barrier init (bar region is untouched by the prologue; launched last
    // for robustness against future aliasing)
    init_bar<<<1, 256, 0, stream>>>(bar);

    // the whole recursion + head in ONE persistent kernel
    trm_persist<<<256, 512, 0, stream>>>(
        xs_hi, xs_lo, h1_hi, h1_lo, bW1t_h, bW1t_l, bW2t_h, bW2t_l,
        bb1, bb2, io, inpf, latf, outf, hw, hb, (float*)d_out, bar);
}